// Round 1
// baseline (960.376 us; speedup 1.0000x reference)
//
#include <hip/hip_runtime.h>
#include <hip/hip_bf16.h>

#define NN 100000     // nodes
#define NE 3200000    // edges
#define NG 512        // graphs
#define IND 128
#define H1D 32
#define H2D 16

// ---------------- workspace layout (element offsets, 4B each) ----------------
#define O_DEG   0u          // int[100352]
#define O_DINV  100352u     // float[100352]
#define O_ROW   200704u     // int[100352]  (needs NN+1)
#define O_CUR   301056u     // int[100352]
#define O_BS    401408u     // int[256]     (98 used)
#define O_GSUM  401664u     // float[512]
#define O_GCNT  402176u     // float[512]
#define O_HA    402688u     // float[3200000]  h1 = x@W1
#define O_F1    3602688u    // float[3200000]  feat1 = relu(agg1+b1)
#define O_H2    6802688u    // float[1600000]  h2 = feat1@W2
#define O_CSR   8402688u    // int[3200000]    csr src indices
// total = 11,602,688 elems = 46.4 MB

__global__ __launch_bounds__(256) void k_init(int* deg, float* gsum, float* gcnt) {
    int i = blockIdx.x * 256 + threadIdx.x;
    if (i < NN) deg[i] = 0;
    if (i < NG) { gsum[i] = 0.f; gcnt[i] = 0.f; }
}

__global__ __launch_bounds__(256) void k_count(const int* dst, int* deg) {
    int e = blockIdx.x * 256 + threadIdx.x;
    if (e < NE) atomicAdd(&deg[dst[e]], 1);
}

// scan over chunks of 1024 (256 threads x 4)
__global__ __launch_bounds__(256) void k_scan1(const int* deg, int* rowstart, int* bs) {
    __shared__ int sd[256];
    int t = threadIdx.x;
    int base = blockIdx.x * 1024 + t * 4;
    int v0 = (base + 0 < NN) ? deg[base + 0] : 0;
    int v1 = (base + 1 < NN) ? deg[base + 1] : 0;
    int v2 = (base + 2 < NN) ? deg[base + 2] : 0;
    int v3 = (base + 3 < NN) ? deg[base + 3] : 0;
    int sum4 = v0 + v1 + v2 + v3;
    sd[t] = sum4;
    __syncthreads();
    for (int off = 1; off < 256; off <<= 1) {
        int val = (t >= off) ? sd[t - off] : 0;
        __syncthreads();
        sd[t] += val;
        __syncthreads();
    }
    int excl = sd[t] - sum4;
    if (base + 0 < NN) rowstart[base + 0] = excl;
    if (base + 1 < NN) rowstart[base + 1] = excl + v0;
    if (base + 2 < NN) rowstart[base + 2] = excl + v0 + v1;
    if (base + 3 < NN) rowstart[base + 3] = excl + v0 + v1 + v2;
    if (t == 255) bs[blockIdx.x] = sd[255];
}

__global__ void k_scan2(int* bs, int nb) {
    int run = 0;
    for (int i = 0; i < nb; ++i) { int v = bs[i]; bs[i] = run; run += v; }
}

__global__ __launch_bounds__(256) void k_scan3(const int* deg, const int* bs,
                                               int* rowstart, int* cursor, float* dinv) {
    int i = blockIdx.x * 256 + threadIdx.x;
    if (i < NN) {
        int rs = rowstart[i] + bs[i >> 10];
        rowstart[i] = rs;
        cursor[i] = rs;
        dinv[i] = 1.0f / sqrtf((float)(deg[i] + 1));  // self-loop => deg>=1
    }
    if (i == 0) rowstart[NN] = NE;
}

__global__ __launch_bounds__(256) void k_fill(const int* src, const int* dst,
                                              int* cursor, int* csr) {
    int e = blockIdx.x * 256 + threadIdx.x;
    if (e < NE) {
        int d = dst[e];
        int pos = atomicAdd(&cursor[d], 1);
        csr[pos] = src[e];
    }
}

// h1 = x @ W1  : [NN,128]x[128,32]
__global__ __launch_bounds__(256) void k_gemm1(const float* __restrict__ x,
                                               const float* __restrict__ W1,
                                               float* __restrict__ h1) {
    __shared__ float sW[IND * H1D];   // 16 KB
    __shared__ float sX[8][IND];      // 4 KB
    int t = threadIdx.x;
    for (int i = t; i < IND * H1D; i += 256) sW[i] = W1[i];
    int nodeBase = blockIdx.x * 8;
    for (int i = t; i < 8 * IND; i += 256) {
        int r = i >> 7, c = i & 127;
        sX[r][c] = x[(nodeBase + r) * IND + c];   // grid exact: 100000/8
    }
    __syncthreads();
    int r = t >> 5, k = t & 31;
    float acc = 0.f;
#pragma unroll 8
    for (int i = 0; i < IND; ++i) acc += sX[r][i] * sW[i * H1D + k];
    h1[(nodeBase + r) * H1D + k] = acc;
}

// feat1[d] = relu( (sum_{s in N(d)} h1[s]*dinv[s]) * dinv[d] + h1[d]*dinv[d]^2 + b1 )
// one wave per dst node; lanes: k = lane&31 (feature), j = lane>>5 (edge slot)
__global__ __launch_bounds__(256) void k_agg1(const float* __restrict__ h1,
                                              const float* __restrict__ dinv,
                                              const int* __restrict__ rowstart,
                                              const int* __restrict__ csr,
                                              const float* __restrict__ b1,
                                              float* __restrict__ feat1) {
    int wave = (blockIdx.x * 256 + threadIdx.x) >> 6;  // node id, 4 per block
    int lane = threadIdx.x & 63;
    int d = wave;
    int k = lane & 31, j = lane >> 5;
    int beg = rowstart[d], end = rowstart[d + 1];
    float acc = 0.f;
    for (int i = beg + j; i < end; i += 2) {
        int s = csr[i];
        acc += h1[s * H1D + k] * dinv[s];
    }
    acc += __shfl_xor(acc, 32);
    float dv = dinv[d];
    float v = acc * dv + h1[d * H1D + k] * dv * dv + b1[k];
    v = fmaxf(v, 0.f);
    if (j == 0) feat1[d * H1D + k] = v;
}

// h2 = feat1 @ W2 : [NN,32]x[32,16]
__global__ __launch_bounds__(256) void k_gemm2(const float* __restrict__ feat1,
                                               const float* __restrict__ W2,
                                               float* __restrict__ h2) {
    __shared__ float sW[H1D * H2D];
    int t = threadIdx.x;
    for (int i = t; i < H1D * H2D; i += 256) sW[i] = W2[i];
    __syncthreads();
    int idx = blockIdx.x * 256 + t;          // grid exact: NN*16/256
    int node = idx >> 4, k = idx & 15;
    const float* row = feat1 + node * H1D;
    float acc = 0.f;
#pragma unroll
    for (int i = 0; i < H1D; ++i) acc += row[i] * sW[i * H2D + k];
    h2[idx] = acc;
}

// layer-2 aggregate + bias + relu + dot(W3) + scatter to graph accumulators
// lanes: k = lane&15 (feature), j = lane>>4 (edge slot, 4-way)
__global__ __launch_bounds__(256) void k_agg2(const float* __restrict__ h2,
                                              const float* __restrict__ dinv,
                                              const int* __restrict__ rowstart,
                                              const int* __restrict__ csr,
                                              const float* __restrict__ b2,
                                              const float* __restrict__ W3,
                                              const int* __restrict__ batch,
                                              float* __restrict__ gsum,
                                              float* __restrict__ gcnt) {
    int wave = (blockIdx.x * 256 + threadIdx.x) >> 6;
    int lane = threadIdx.x & 63;
    int d = wave;
    int k = lane & 15, j = lane >> 4;
    int beg = rowstart[d], end = rowstart[d + 1];
    float acc = 0.f;
    for (int i = beg + j; i < end; i += 4) {
        int s = csr[i];
        acc += h2[s * H2D + k] * dinv[s];
    }
    acc += __shfl_xor(acc, 16);
    acc += __shfl_xor(acc, 32);
    float dv = dinv[d];
    float v = acc * dv + h2[d * H2D + k] * dv * dv + b2[k];
    v = fmaxf(v, 0.f);
    float partial = v * W3[k];
    partial += __shfl_xor(partial, 1);
    partial += __shfl_xor(partial, 2);
    partial += __shfl_xor(partial, 4);
    partial += __shfl_xor(partial, 8);
    if (lane == 0) {
        int g = batch[d];
        atomicAdd(&gsum[g], partial);
        atomicAdd(&gcnt[g], 1.0f);
    }
}

__global__ __launch_bounds__(256) void k_final(const float* gsum, const float* gcnt,
                                               const float* b3, float* out) {
    int g = blockIdx.x * 256 + threadIdx.x;
    if (g < NG) out[g] = gsum[g] / fmaxf(gcnt[g], 1.0f) + b3[0];
}

extern "C" void kernel_launch(void* const* d_in, const int* in_sizes, int n_in,
                              void* d_out, int out_size, void* d_ws, size_t ws_size,
                              hipStream_t stream) {
    const float* x   = (const float*)d_in[0];
    const int*   src = (const int*)d_in[1];
    const int*   dst = src + NE;
    const int*   batch = (const int*)d_in[2];
    const float* W1 = (const float*)d_in[3];
    const float* b1 = (const float*)d_in[4];
    const float* W2 = (const float*)d_in[5];
    const float* b2 = (const float*)d_in[6];
    const float* W3 = (const float*)d_in[7];
    const float* b3 = (const float*)d_in[8];
    float* out = (float*)d_out;

    float* ws = (float*)d_ws;
    int*   deg      = (int*)(ws + O_DEG);
    float* dinv     = ws + O_DINV;
    int*   rowstart = (int*)(ws + O_ROW);
    int*   cursor   = (int*)(ws + O_CUR);
    int*   bs       = (int*)(ws + O_BS);
    float* gsum     = ws + O_GSUM;
    float* gcnt     = ws + O_GCNT;
    float* h1       = ws + O_HA;
    float* feat1    = ws + O_F1;
    float* h2       = ws + O_H2;
    int*   csr      = (int*)(ws + O_CSR);

    const int nScanBlocks = (NN + 1023) / 1024;  // 98

    k_init <<<(NN + 255) / 256, 256, 0, stream>>>(deg, gsum, gcnt);
    k_count<<<(NE + 255) / 256, 256, 0, stream>>>(dst, deg);
    k_scan1<<<nScanBlocks, 256, 0, stream>>>(deg, rowstart, bs);
    k_scan2<<<1, 1, 0, stream>>>(bs, nScanBlocks);
    k_scan3<<<(NN + 255) / 256, 256, 0, stream>>>(deg, bs, rowstart, cursor, dinv);
    k_fill <<<(NE + 255) / 256, 256, 0, stream>>>(src, dst, cursor, csr);

    k_gemm1<<<NN / 8, 256, 0, stream>>>(x, W1, h1);
    k_agg1 <<<NN / 4, 256, 0, stream>>>(h1, dinv, rowstart, csr, b1, feat1);
    k_gemm2<<<NN * H2D / 256, 256, 0, stream>>>(feat1, W2, h2);
    k_agg2 <<<NN / 4, 256, 0, stream>>>(h2, dinv, rowstart, csr, b2, W3, batch, gsum, gcnt);
    k_final<<<(NG + 255) / 256, 256, 0, stream>>>(gsum, gcnt, b3, out);
}